// Round 1
// baseline (8932.987 us; speedup 1.0000x reference)
//
#include <hip/hip_runtime.h>
#include <math.h>

// GRUDecoder (NRI decoder) on MI355X — round 1: fp32 correctness baseline.
// Factorization: msg_fc1 computed per-node (U,V), edge kernel does only
// relu(U_i+V_j+b1) -> msg_fc2 -> *type_sum -> per-receiver reduction.

namespace {
constexpr int kB = 16, kT = 40, kTS = 39, kN = 64, kDin = 64, kH = 256;
constexpr int kE = kN * (kN - 1);   // 4032
constexpr int kBN = kB * kN;        // 1024
constexpr int kDout = 64;
constexpr int kKT = 64;             // K tile in edge kernel
constexpr int kGR = 4;              // rows per block in gru_uv kernel
constexpr int kOR = 32;             // rows per block in out_mlp kernel
}

__device__ __forceinline__ float sigm(float x) { return 1.f / (1.f + expf(-x)); }

// ---------------- setup: edge table + type sums ----------------
__global__ void setup_kernel(const float* __restrict__ rel_rec,
                             const float* __restrict__ rel_send,
                             const float* __restrict__ rel_types,
                             int* __restrict__ edge_at, float* __restrict__ ts) {
    int idx = blockIdx.x * 256 + threadIdx.x;
    if (idx < kE) {
        int si = 0, ri = 0;
        for (int n = 0; n < kN; ++n) {
            if (rel_send[idx * kN + n] > 0.5f) si = n;
            if (rel_rec[idx * kN + n] > 0.5f) ri = n;
        }
        edge_at[ri * kN + si] = idx;
    }
    if (idx < kB * kE) ts[idx] = rel_types[2 * idx] + rel_types[2 * idx + 1];
}

// ---------------- per-step: edge messages + aggregation ----------------
// One block per (b, receiver j). 512 threads.
// agg[b,j,h] = sum_i ts(i->j) * relu( W2 @ relu(U[b,i]+V[b,j]+b1) + b2 )[h]
__global__ __launch_bounds__(512)
void edge_kernel(const float* __restrict__ U, const float* __restrict__ V,
                 const float* __restrict__ W2, const float* __restrict__ b1,
                 const float* __restrict__ b2, const float* __restrict__ ts,
                 const int* __restrict__ edge_at, float* __restrict__ agg) {
    __shared__ float h1[kN][kH];        // 64 KiB, [sender i][k]
    __shared__ float w2s[kKT][kH + 1];  // 64.25 KiB, [kk][h], pad -> conflict-free
    __shared__ float red[8][kH];        // 8 KiB
    const int blk = blockIdx.x, b = blk >> 6, j = blk & 63;
    const int tid = threadIdx.x;

    // phase 1: build h1 (row j zeroed; its ts is 0 anyway)
    {
        const int k = tid & 255, ih = tid >> 8;
        const float vj = V[(b * kN + j) * kH + k] + b1[k];
        #pragma unroll 8
        for (int i = ih * 32; i < ih * 32 + 32; ++i) {
            float u = U[(b * kN + i) * kH + k];
            h1[i][k] = (i == j) ? 0.f : fmaxf(u + vj, 0.f);
        }
    }

    const int th = tid & 63, ti = tid >> 6;   // ti wave-uniform -> h1 reads broadcast
    float acc[8][4];
    #pragma unroll
    for (int r = 0; r < 8; ++r)
        #pragma unroll
        for (int c = 0; c < 4; ++c) acc[r][c] = 0.f;

    for (int kt = 0; kt < kH; kt += kKT) {
        __syncthreads();
        // stage W2[:, kt:kt+64] transposed: w2s[kk][h]
        for (int x = tid; x < kKT * kH; x += 512) {
            int kk = x & (kKT - 1), h = x >> 6;
            w2s[kk][h] = W2[h * kH + kt + kk];
        }
        __syncthreads();
        #pragma unroll 2
        for (int kk = 0; kk < kKT; ++kk) {
            float bb[4], a[8];
            #pragma unroll
            for (int c = 0; c < 4; ++c) bb[c] = w2s[kk][th + 64 * c];
            #pragma unroll
            for (int r = 0; r < 8; ++r) a[r] = h1[ti * 8 + r][kt + kk];
            #pragma unroll
            for (int r = 0; r < 8; ++r)
                #pragma unroll
                for (int c = 0; c < 4; ++c) acc[r][c] += a[r] * bb[c];
        }
    }

    // epilogue: relu(+b2), weight by type-sum, reduce over senders
    float tsv[8];
    #pragma unroll
    for (int r = 0; r < 8; ++r) {
        int e = edge_at[j * kN + ti * 8 + r];
        tsv[r] = (e < 0) ? 0.f : ts[b * kE + e];
    }
    #pragma unroll
    for (int c = 0; c < 4; ++c) {
        const int h = th + 64 * c;
        const float bv = b2[h];
        float s = 0.f;
        #pragma unroll
        for (int r = 0; r < 8; ++r) s += tsv[r] * fmaxf(acc[r][c] + bv, 0.f);
        red[ti][h] = s;
    }
    __syncthreads();
    if (tid < kH) {
        float s = 0.f;
        #pragma unroll
        for (int r = 0; r < 8; ++r) s += red[r][tid];
        agg[(b * kN + j) * kH + tid] = s;
    }
}

// ---------------- per-step: GRU update + next-step U,V ----------------
// One block per kGR rows (row = b*64+n). 256 threads, thread o = output idx.
__global__ __launch_bounds__(256)
void gru_uv_kernel(const float* __restrict__ hprev, const float* __restrict__ agg,
                   const float* __restrict__ inputs, int t,
                   const float* __restrict__ Wir, const float* __restrict__ bir,
                   const float* __restrict__ Whr, const float* __restrict__ bhr,
                   const float* __restrict__ Wii, const float* __restrict__ bii,
                   const float* __restrict__ Whi, const float* __restrict__ bhi,
                   const float* __restrict__ Win, const float* __restrict__ bin_,
                   const float* __restrict__ Whn, const float* __restrict__ bhn,
                   const float* __restrict__ W1,
                   float* __restrict__ hnew, float* __restrict__ Uo,
                   float* __restrict__ Vo) {
    __shared__ float hp[kGR][kH], ag[kGR][kH], xl[kGR][kDin], hn[kGR][kH];
    const int m0 = blockIdx.x * kGR;
    const int tid = threadIdx.x;
    for (int x = tid; x < kGR * kH; x += 256) {
        int r = x >> 8, k = x & 255;
        hp[r][k] = hprev[(m0 + r) * kH + k];
        ag[r][k] = agg[(m0 + r) * kH + k];
    }
    {
        int r = tid >> 6, k = tid & 63;
        int m = m0 + r, b = m >> 6, n = m & 63;
        xl[r][k] = inputs[((b * kT + t) * kN + n) * kDin + k];
    }
    __syncthreads();

    const int o = tid;
    float ar[kGR] = {}, ai[kGR] = {}, an[kGR] = {};
    {
        const float4* Whr4 = (const float4*)(Whr + o * kH);
        const float4* Whi4 = (const float4*)(Whi + o * kH);
        const float4* Whn4 = (const float4*)(Whn + o * kH);
        #pragma unroll 4
        for (int k4 = 0; k4 < kH / 4; ++k4) {
            float4 wr = Whr4[k4], wi = Whi4[k4], wn = Whn4[k4];
            #pragma unroll
            for (int r = 0; r < kGR; ++r) {
                float4 av = *(const float4*)&ag[r][k4 * 4];
                ar[r] += wr.x * av.x + wr.y * av.y + wr.z * av.z + wr.w * av.w;
                ai[r] += wi.x * av.x + wi.y * av.y + wi.z * av.z + wi.w * av.w;
                an[r] += wn.x * av.x + wn.y * av.y + wn.z * av.z + wn.w * av.w;
            }
        }
    }
    float xr[kGR] = {}, xi[kGR] = {}, xn[kGR] = {};
    {
        const float4* Wir4 = (const float4*)(Wir + o * kDin);
        const float4* Wii4 = (const float4*)(Wii + o * kDin);
        const float4* Win4 = (const float4*)(Win + o * kDin);
        #pragma unroll 4
        for (int k4 = 0; k4 < kDin / 4; ++k4) {
            float4 wr = Wir4[k4], wi = Wii4[k4], wn = Win4[k4];
            #pragma unroll
            for (int r = 0; r < kGR; ++r) {
                float4 xv = *(const float4*)&xl[r][k4 * 4];
                xr[r] += wr.x * xv.x + wr.y * xv.y + wr.z * xv.z + wr.w * xv.w;
                xi[r] += wi.x * xv.x + wi.y * xv.y + wi.z * xv.z + wi.w * xv.w;
                xn[r] += wn.x * xv.x + wn.y * xv.y + wn.z * xv.z + wn.w * xv.w;
            }
        }
    }
    const float b_ir = bir[o], b_hr = bhr[o], b_ii = bii[o], b_hi = bhi[o];
    const float b_in = bin_[o], b_hn = bhn[o];
    #pragma unroll
    for (int r = 0; r < kGR; ++r) {
        float rg = sigm(xr[r] + b_ir + ar[r] + b_hr);
        float ig = sigm(xi[r] + b_ii + ai[r] + b_hi);
        float ng = tanhf(xn[r] + b_in + rg * (an[r] + b_hn));
        float h2 = (1.f - ig) * ng + ig * hp[r][o];
        hn[r][o] = h2;
        hnew[(m0 + r) * kH + o] = h2;
    }
    __syncthreads();

    // next-step U,V (msg_fc1 split: first 256 cols -> sender U, last -> receiver V)
    float au[kGR] = {}, av_[kGR] = {};
    {
        const float4* W1u4 = (const float4*)(W1 + o * 2 * kH);
        const float4* W1v4 = (const float4*)(W1 + o * 2 * kH + kH);
        #pragma unroll 4
        for (int k4 = 0; k4 < kH / 4; ++k4) {
            float4 wu = W1u4[k4], wv = W1v4[k4];
            #pragma unroll
            for (int r = 0; r < kGR; ++r) {
                float4 hv = *(const float4*)&hn[r][k4 * 4];
                au[r] += wu.x * hv.x + wu.y * hv.y + wu.z * hv.z + wu.w * hv.w;
                av_[r] += wv.x * hv.x + wv.y * hv.y + wv.z * hv.z + wv.w * hv.w;
            }
        }
    }
    #pragma unroll
    for (int r = 0; r < kGR; ++r) {
        Uo[(m0 + r) * kH + o] = au[r];
        Vo[(m0 + r) * kH + o] = av_[r];
    }
}

// ---------------- batched output MLP over all timesteps ----------------
// Row m = t*1024 + b*64 + n, reads hidden history, writes preds.
__global__ __launch_bounds__(256)
void out_mlp_kernel(const float* __restrict__ hist,
                    const float* __restrict__ fc1w, const float* __restrict__ fc1b,
                    const float* __restrict__ fc2w, const float* __restrict__ fc2b,
                    const float* __restrict__ fc3w, const float* __restrict__ fc3b,
                    float* __restrict__ out) {
    __shared__ float bufA[kOR][kH];   // 32 KiB
    __shared__ float bufB[kOR][kH];   // 32 KiB
    const int m0 = blockIdx.x * kOR;
    const int tid = threadIdx.x;
    for (int x = tid; x < kOR * kH; x += 256) {
        int r = x >> 8, k = x & 255;
        bufA[r][k] = hist[(m0 + r) * kH + k];
    }
    __syncthreads();

    const int oc = tid & 127;   // handles cols oc and oc+128
    const int rg = tid >> 7;    // row half: rows rg*16 .. +15

    // fc1: bufA -> bufB
    {
        float a0[16] = {}, a1[16] = {};
        const float4* w04 = (const float4*)(fc1w + oc * kH);
        const float4* w14 = (const float4*)(fc1w + (oc + 128) * kH);
        #pragma unroll 2
        for (int k4 = 0; k4 < kH / 4; ++k4) {
            float4 w0 = w04[k4], w1 = w14[k4];
            #pragma unroll
            for (int r = 0; r < 16; ++r) {
                float4 av = *(const float4*)&bufA[rg * 16 + r][k4 * 4];
                a0[r] += w0.x * av.x + w0.y * av.y + w0.z * av.z + w0.w * av.w;
                a1[r] += w1.x * av.x + w1.y * av.y + w1.z * av.z + w1.w * av.w;
            }
        }
        float c0 = fc1b[oc], c1 = fc1b[oc + 128];
        #pragma unroll
        for (int r = 0; r < 16; ++r) {
            bufB[rg * 16 + r][oc] = fmaxf(a0[r] + c0, 0.f);
            bufB[rg * 16 + r][oc + 128] = fmaxf(a1[r] + c1, 0.f);
        }
    }
    __syncthreads();
    // fc2: bufB -> bufA
    {
        float a0[16] = {}, a1[16] = {};
        const float4* w04 = (const float4*)(fc2w + oc * kH);
        const float4* w14 = (const float4*)(fc2w + (oc + 128) * kH);
        #pragma unroll 2
        for (int k4 = 0; k4 < kH / 4; ++k4) {
            float4 w0 = w04[k4], w1 = w14[k4];
            #pragma unroll
            for (int r = 0; r < 16; ++r) {
                float4 av = *(const float4*)&bufB[rg * 16 + r][k4 * 4];
                a0[r] += w0.x * av.x + w0.y * av.y + w0.z * av.z + w0.w * av.w;
                a1[r] += w1.x * av.x + w1.y * av.y + w1.z * av.z + w1.w * av.w;
            }
        }
        float c0 = fc2b[oc], c1 = fc2b[oc + 128];
        #pragma unroll
        for (int r = 0; r < 16; ++r) {
            bufA[rg * 16 + r][oc] = fmaxf(a0[r] + c0, 0.f);
            bufA[rg * 16 + r][oc + 128] = fmaxf(a1[r] + c1, 0.f);
        }
    }
    __syncthreads();
    // fc3: bufA -> out (k split over 4 thread groups, reduce via bufB)
    {
        const int o3 = tid & 63, kg = tid >> 6;
        float acc[kOR] = {};
        const float4* w4 = (const float4*)(fc3w + o3 * kH + kg * 64);
        #pragma unroll 2
        for (int k4 = 0; k4 < 16; ++k4) {
            float4 wv = w4[k4];
            #pragma unroll
            for (int r = 0; r < kOR; ++r) {
                float4 av = *(const float4*)&bufA[r][kg * 64 + k4 * 4];
                acc[r] += wv.x * av.x + wv.y * av.y + wv.z * av.z + wv.w * av.w;
            }
        }
        float* red = &bufB[0][0];   // 4*kOR*64 == kOR*kH floats
        #pragma unroll
        for (int r = 0; r < kOR; ++r) red[(kg * kOR + r) * 64 + o3] = acc[r];
        __syncthreads();
        for (int x = tid; x < kOR * 64; x += 256) {
            int r = x >> 6, o = x & 63;
            float s = red[r * 64 + o] + red[(kOR + r) * 64 + o] +
                      red[(2 * kOR + r) * 64 + o] + red[(3 * kOR + r) * 64 + o] +
                      fc3b[o];
            int m = m0 + r;
            int t = m >> 10, bn = m & 1023, b = bn >> 6, n = bn & 63;
            out[((b * kTS + t) * kN + n) * kDout + o] = s;
        }
    }
}

extern "C" void kernel_launch(void* const* d_in, const int* in_sizes, int n_in,
                              void* d_out, int out_size, void* d_ws, size_t ws_size,
                              hipStream_t stream) {
    const float* inputs    = (const float*)d_in[0];
    const float* rel_rec   = (const float*)d_in[1];
    const float* rel_send  = (const float*)d_in[2];
    const float* rel_types = (const float*)d_in[3];
    const float* W1  = (const float*)d_in[4];  const float* b1  = (const float*)d_in[5];
    const float* W2  = (const float*)d_in[6];  const float* b2  = (const float*)d_in[7];
    const float* Wir = (const float*)d_in[8];  const float* bir = (const float*)d_in[9];
    const float* Whr = (const float*)d_in[10]; const float* bhr = (const float*)d_in[11];
    const float* Wii = (const float*)d_in[12]; const float* bii = (const float*)d_in[13];
    const float* Whi = (const float*)d_in[14]; const float* bhi = (const float*)d_in[15];
    const float* Win = (const float*)d_in[16]; const float* bin_ = (const float*)d_in[17];
    const float* Whn = (const float*)d_in[18]; const float* bhn = (const float*)d_in[19];
    const float* fc1w = (const float*)d_in[20]; const float* fc1b = (const float*)d_in[21];
    const float* fc2w = (const float*)d_in[22]; const float* fc2b = (const float*)d_in[23];
    const float* fc3w = (const float*)d_in[24]; const float* fc3b = (const float*)d_in[25];
    float* out = (float*)d_out;

    char* w = (char*)d_ws;
    int* edge_at = (int*)w;            w += ((kN * kN * 4 + 255) / 256) * 256;
    float* ts = (float*)w;             w += ((kB * kE * 4 + 255) / 256) * 256;
    float* U = (float*)w;              w += kBN * kH * 4;
    float* V = (float*)w;              w += kBN * kH * 4;
    float* agg = (float*)w;            w += kBN * kH * 4;
    float* hh = (float*)w;             // (kTS+1) * kBN * kH floats (~42 MiB)

    hipMemsetAsync(edge_at, 0xFF, kN * kN * 4, stream);
    setup_kernel<<<(kB * kE + 255) / 256, 256, 0, stream>>>(rel_rec, rel_send,
                                                            rel_types, edge_at, ts);
    hipMemsetAsync(U, 0, kBN * kH * 4, stream);
    hipMemsetAsync(V, 0, kBN * kH * 4, stream);
    hipMemsetAsync(hh, 0, kBN * kH * 4, stream);   // h_0 = 0

    for (int t = 0; t < kTS; ++t) {
        edge_kernel<<<kBN, 512, 0, stream>>>(U, V, W2, b1, b2, ts, edge_at, agg);
        gru_uv_kernel<<<kBN / kGR, 256, 0, stream>>>(
            hh + (size_t)t * kBN * kH, agg, inputs, t,
            Wir, bir, Whr, bhr, Wii, bii, Whi, bhi, Win, bin_, Whn, bhn, W1,
            hh + (size_t)(t + 1) * kBN * kH, U, V);
    }
    out_mlp_kernel<<<kTS * kBN / kOR, 256, 0, stream>>>(
        hh + (size_t)kBN * kH, fc1w, fc1b, fc2w, fc2b, fc3w, fc3b, out);
}

// Round 3
// 3790.403 us; speedup vs baseline: 2.3567x; 2.3567x over previous
//
#include <hip/hip_runtime.h>
#include <math.h>

// GRUDecoder (NRI decoder) on MI355X — round 3: split-bf16 MFMA edge kernel.
// Precision fix for round 2: operands as hi+lo bf16 pairs, 3-term MFMA
// (Ah*Bh + Al*Bh + Ah*Bl) ~ fp32 accuracy at bf16 MFMA rate.

namespace {
constexpr int kB = 16, kT = 40, kTS = 39, kN = 64, kDin = 64, kH = 256;
constexpr int kE = kN * (kN - 1);   // 4032
constexpr int kBN = kB * kN;        // 1024
constexpr int kDout = 64;
constexpr int kGR = 4;              // rows per block in gru_uv kernel
constexpr int kOR = 32;             // rows per block in out_mlp kernel
}

typedef short short8 __attribute__((ext_vector_type(8)));
typedef float f32x4 __attribute__((ext_vector_type(4)));

__device__ __forceinline__ float sigm(float x) { return 1.f / (1.f + expf(-x)); }

__device__ __forceinline__ unsigned short f2bf(float x) {
    unsigned int u = __float_as_uint(x);
    u = (u + 0x7fffu + ((u >> 16) & 1u)) >> 16;   // RNE
    return (unsigned short)u;
}
__device__ __forceinline__ float bf2f(unsigned short h) {
    return __uint_as_float((unsigned)h << 16);
}

// ---------------- setup: edge table + type sums + W2 -> bf16 hi/lo ---------
__global__ void setup_kernel(const float* __restrict__ rel_rec,
                             const float* __restrict__ rel_send,
                             const float* __restrict__ rel_types,
                             const float* __restrict__ W2,
                             int* __restrict__ edge_at, float* __restrict__ ts,
                             unsigned short* __restrict__ W2h,
                             unsigned short* __restrict__ W2l) {
    int idx = blockIdx.x * 256 + threadIdx.x;
    if (idx < kE) {
        int si = 0, ri = 0;
        for (int n = 0; n < kN; ++n) {
            if (rel_send[idx * kN + n] > 0.5f) si = n;
            if (rel_rec[idx * kN + n] > 0.5f) ri = n;
        }
        edge_at[ri * kN + si] = idx;
    }
    if (idx < kB * kE) ts[idx] = rel_types[2 * idx] + rel_types[2 * idx + 1];
    if (idx < kH * kH) {
        float wv = W2[idx];
        unsigned short h = f2bf(wv);
        W2h[idx] = h;
        W2l[idx] = f2bf(wv - bf2f(h));
    }
}

// ---------------- per-step: edge messages + aggregation (split-bf16 MFMA) --
// One block per (b, receiver j). 256 threads = 4 waves.
// Wave w computes output cols [64w, 64w+64) for all 64 senders (M=64, K=256),
// then reduces over senders with type-sum weights.
__global__ __launch_bounds__(256)
void edge_kernel(const float* __restrict__ U, const float* __restrict__ V,
                 const unsigned short* __restrict__ W2h,
                 const unsigned short* __restrict__ W2l,
                 const float* __restrict__ b1, const float* __restrict__ b2,
                 const float* __restrict__ ts, const int* __restrict__ edge_at,
                 float* __restrict__ agg) {
    __shared__ __align__(16) unsigned short h1h[kN * kH];  // 32 KiB, swizzled
    __shared__ __align__(16) unsigned short h1l[kN * kH];  // 32 KiB, swizzled
    __shared__ float vjb[kH];
    __shared__ float tss[kN];
    const int blk = blockIdx.x, b = blk >> 6, j = blk & 63;
    const int tid = threadIdx.x;

    if (tid < kN) {
        int e = edge_at[j * kN + tid];
        tss[tid] = (e < 0) ? 0.f : ts[b * kE + e];
    }
    vjb[tid] = V[(b * kN + j) * kH + tid] + b1[tid];
    __syncthreads();

    // ---- build h1 = relu(U_i + vjb) as hi/lo bf16, swizzle byte ^=(row&7)<<4
    {
        const int o = tid & 31, i0 = tid >> 5;   // k-octet o, starting row
        const int k0 = o * 8;
        const float4 vj0 = *(const float4*)&vjb[k0];
        const float4 vj1 = *(const float4*)&vjb[k0 + 4];
        #pragma unroll
        for (int p = 0; p < 8; ++p) {
            const int i = i0 + 8 * p;
            const float4* up = (const float4*)(U + (b * kN + i) * kH + k0);
            float4 f0 = up[0], f1 = up[1];
            float x[8] = {f0.x + vj0.x, f0.y + vj0.y, f0.z + vj0.z, f0.w + vj0.w,
                          f1.x + vj1.x, f1.y + vj1.y, f1.z + vj1.z, f1.w + vj1.w};
            unsigned hi[8], lo[8];
            #pragma unroll
            for (int q = 0; q < 8; ++q) {
                float xv = (i == j) ? 0.f : fmaxf(x[q], 0.f);
                unsigned short hv = f2bf(xv);
                hi[q] = hv;
                lo[q] = f2bf(xv - bf2f(hv));
            }
            uint4 ph, pl;
            ph.x = hi[0] | (hi[1] << 16); ph.y = hi[2] | (hi[3] << 16);
            ph.z = hi[4] | (hi[5] << 16); ph.w = hi[6] | (hi[7] << 16);
            pl.x = lo[0] | (lo[1] << 16); pl.y = lo[2] | (lo[3] << 16);
            pl.z = lo[4] | (lo[5] << 16); pl.w = lo[6] | (lo[7] << 16);
            const int byte = i * 512 + ((k0 * 2) ^ ((i & 7) << 4));
            *(uint4*)((char*)h1h + byte) = ph;
            *(uint4*)((char*)h1l + byte) = pl;
        }
    }
    __syncthreads();

    // ---- MFMA: out[i][col] = sum_k h1[i][k] * W2[col][k], 3-term split
    const int lane = tid & 63, w = tid >> 6;
    const int mrow = lane & 15, mq = lane >> 4;
    f32x4 acc[4][4];
    #pragma unroll
    for (int mf = 0; mf < 4; ++mf)
        #pragma unroll
        for (int nf = 0; nf < 4; ++nf) acc[mf][nf] = (f32x4){0.f, 0.f, 0.f, 0.f};

    const size_t woff = (size_t)(w * 64 + mrow) * kH + mq * 8;
    const unsigned short* Wph = W2h + woff;
    const unsigned short* Wpl = W2l + woff;
    #pragma unroll
    for (int kt = 0; kt < 8; ++kt) {
        const int k0 = kt * 32;
        short8 ah[4], al[4], bh_[4], bl_[4];
        #pragma unroll
        for (int mf = 0; mf < 4; ++mf) {
            const int r = mf * 16 + mrow;
            const int byte = r * 512 + (((k0 + mq * 8) * 2) ^ ((r & 7) << 4));
            ah[mf] = *(const short8*)((const char*)h1h + byte);
            al[mf] = *(const short8*)((const char*)h1l + byte);
        }
        #pragma unroll
        for (int nf = 0; nf < 4; ++nf) {
            bh_[nf] = *(const short8*)(Wph + nf * 16 * kH + k0);
            bl_[nf] = *(const short8*)(Wpl + nf * 16 * kH + k0);
        }
        #pragma unroll
        for (int mf = 0; mf < 4; ++mf)
            #pragma unroll
            for (int nf = 0; nf < 4; ++nf) {
                acc[mf][nf] = __builtin_amdgcn_mfma_f32_16x16x32_bf16(
                    ah[mf], bh_[nf], acc[mf][nf], 0, 0, 0);
                acc[mf][nf] = __builtin_amdgcn_mfma_f32_16x16x32_bf16(
                    al[mf], bh_[nf], acc[mf][nf], 0, 0, 0);
                acc[mf][nf] = __builtin_amdgcn_mfma_f32_16x16x32_bf16(
                    ah[mf], bl_[nf], acc[mf][nf], 0, 0, 0);
            }
    }

    // ---- epilogue: relu(+b2), ts-weight, reduce over senders (M)
    float tsr[16];
    #pragma unroll
    for (int mf = 0; mf < 4; ++mf)
        #pragma unroll
        for (int r = 0; r < 4; ++r)
            tsr[mf * 4 + r] = tss[mf * 16 + mq * 4 + r];   // D row = (lane>>4)*4+r
    #pragma unroll
    for (int nf = 0; nf < 4; ++nf) {
        const int col = w * 64 + nf * 16 + mrow;
        const float bv = b2[col];
        float s = 0.f;
        #pragma unroll
        for (int mf = 0; mf < 4; ++mf)
            #pragma unroll
            for (int r = 0; r < 4; ++r)
                s += tsr[mf * 4 + r] * fmaxf(acc[mf][nf][r] + bv, 0.f);
        s += __shfl_xor(s, 16);
        s += __shfl_xor(s, 32);
        if (lane < 16) agg[(b * kN + j) * kH + col] = s;
    }
}

// ---------------- per-step: GRU update + next-step U,V ----------------
__global__ __launch_bounds__(256)
void gru_uv_kernel(const float* __restrict__ hprev, const float* __restrict__ agg,
                   const float* __restrict__ inputs, int t,
                   const float* __restrict__ Wir, const float* __restrict__ bir,
                   const float* __restrict__ Whr, const float* __restrict__ bhr,
                   const float* __restrict__ Wii, const float* __restrict__ bii,
                   const float* __restrict__ Whi, const float* __restrict__ bhi,
                   const float* __restrict__ Win, const float* __restrict__ bin_,
                   const float* __restrict__ Whn, const float* __restrict__ bhn,
                   const float* __restrict__ W1,
                   float* __restrict__ hnew, float* __restrict__ Uo,
                   float* __restrict__ Vo) {
    __shared__ float hp[kGR][kH], ag[kGR][kH], xl[kGR][kDin], hn[kGR][kH];
    const int m0 = blockIdx.x * kGR;
    const int tid = threadIdx.x;
    for (int x = tid; x < kGR * kH; x += 256) {
        int r = x >> 8, k = x & 255;
        hp[r][k] = hprev[(m0 + r) * kH + k];
        ag[r][k] = agg[(m0 + r) * kH + k];
    }
    {
        int r = tid >> 6, k = tid & 63;
        int m = m0 + r, b = m >> 6, n = m & 63;
        xl[r][k] = inputs[((b * kT + t) * kN + n) * kDin + k];
    }
    __syncthreads();

    const int o = tid;
    float ar[kGR] = {}, ai[kGR] = {}, an[kGR] = {};
    {
        const float4* Whr4 = (const float4*)(Whr + o * kH);
        const float4* Whi4 = (const float4*)(Whi + o * kH);
        const float4* Whn4 = (const float4*)(Whn + o * kH);
        #pragma unroll 4
        for (int k4 = 0; k4 < kH / 4; ++k4) {
            float4 wr = Whr4[k4], wi = Whi4[k4], wn = Whn4[k4];
            #pragma unroll
            for (int r = 0; r < kGR; ++r) {
                float4 av = *(const float4*)&ag[r][k4 * 4];
                ar[r] += wr.x * av.x + wr.y * av.y + wr.z * av.z + wr.w * av.w;
                ai[r] += wi.x * av.x + wi.y * av.y + wi.z * av.z + wi.w * av.w;
                an[r] += wn.x * av.x + wn.y * av.y + wn.z * av.z + wn.w * av.w;
            }
        }
    }
    float xr[kGR] = {}, xi[kGR] = {}, xn[kGR] = {};
    {
        const float4* Wir4 = (const float4*)(Wir + o * kDin);
        const float4* Wii4 = (const float4*)(Wii + o * kDin);
        const float4* Win4 = (const float4*)(Win + o * kDin);
        #pragma unroll 4
        for (int k4 = 0; k4 < kDin / 4; ++k4) {
            float4 wr = Wir4[k4], wi = Wii4[k4], wn = Win4[k4];
            #pragma unroll
            for (int r = 0; r < kGR; ++r) {
                float4 xv = *(const float4*)&xl[r][k4 * 4];
                xr[r] += wr.x * xv.x + wr.y * xv.y + wr.z * xv.z + wr.w * xv.w;
                xi[r] += wi.x * xv.x + wi.y * xv.y + wi.z * xv.z + wi.w * xv.w;
                xn[r] += wn.x * xv.x + wn.y * xv.y + wn.z * xv.z + wn.w * xv.w;
            }
        }
    }
    const float b_ir = bir[o], b_hr = bhr[o], b_ii = bii[o], b_hi = bhi[o];
    const float b_in = bin_[o], b_hn = bhn[o];
    #pragma unroll
    for (int r = 0; r < kGR; ++r) {
        float rg = sigm(xr[r] + b_ir + ar[r] + b_hr);
        float ig = sigm(xi[r] + b_ii + ai[r] + b_hi);
        float ng = tanhf(xn[r] + b_in + rg * (an[r] + b_hn));
        float h2 = (1.f - ig) * ng + ig * hp[r][o];
        hn[r][o] = h2;
        hnew[(m0 + r) * kH + o] = h2;
    }
    __syncthreads();

    float au[kGR] = {}, av_[kGR] = {};
    {
        const float4* W1u4 = (const float4*)(W1 + o * 2 * kH);
        const float4* W1v4 = (const float4*)(W1 + o * 2 * kH + kH);
        #pragma unroll 4
        for (int k4 = 0; k4 < kH / 4; ++k4) {
            float4 wu = W1u4[k4], wv = W1v4[k4];
            #pragma unroll
            for (int r = 0; r < kGR; ++r) {
                float4 hv = *(const float4*)&hn[r][k4 * 4];
                au[r] += wu.x * hv.x + wu.y * hv.y + wu.z * hv.z + wu.w * hv.w;
                av_[r] += wv.x * hv.x + wv.y * hv.y + wv.z * hv.z + wv.w * hv.w;
            }
        }
    }
    #pragma unroll
    for (int r = 0; r < kGR; ++r) {
        Uo[(m0 + r) * kH + o] = au[r];
        Vo[(m0 + r) * kH + o] = av_[r];
    }
}

// ---------------- batched output MLP over all timesteps ----------------
__global__ __launch_bounds__(256)
void out_mlp_kernel(const float* __restrict__ hist,
                    const float* __restrict__ fc1w, const float* __restrict__ fc1b,
                    const float* __restrict__ fc2w, const float* __restrict__ fc2b,
                    const float* __restrict__ fc3w, const float* __restrict__ fc3b,
                    float* __restrict__ out) {
    __shared__ float bufA[kOR][kH];
    __shared__ float bufB[kOR][kH];
    const int m0 = blockIdx.x * kOR;
    const int tid = threadIdx.x;
    for (int x = tid; x < kOR * kH; x += 256) {
        int r = x >> 8, k = x & 255;
        bufA[r][k] = hist[(m0 + r) * kH + k];
    }
    __syncthreads();

    const int oc = tid & 127;
    const int rg = tid >> 7;

    {
        float a0[16] = {}, a1[16] = {};
        const float4* w04 = (const float4*)(fc1w + oc * kH);
        const float4* w14 = (const float4*)(fc1w + (oc + 128) * kH);
        #pragma unroll 2
        for (int k4 = 0; k4 < kH / 4; ++k4) {
            float4 w0 = w04[k4], w1 = w14[k4];
            #pragma unroll
            for (int r = 0; r < 16; ++r) {
                float4 av = *(const float4*)&bufA[rg * 16 + r][k4 * 4];
                a0[r] += w0.x * av.x + w0.y * av.y + w0.z * av.z + w0.w * av.w;
                a1[r] += w1.x * av.x + w1.y * av.y + w1.z * av.z + w1.w * av.w;
            }
        }
        float c0 = fc1b[oc], c1 = fc1b[oc + 128];
        #pragma unroll
        for (int r = 0; r < 16; ++r) {
            bufB[rg * 16 + r][oc] = fmaxf(a0[r] + c0, 0.f);
            bufB[rg * 16 + r][oc + 128] = fmaxf(a1[r] + c1, 0.f);
        }
    }
    __syncthreads();
    {
        float a0[16] = {}, a1[16] = {};
        const float4* w04 = (const float4*)(fc2w + oc * kH);
        const float4* w14 = (const float4*)(fc2w + (oc + 128) * kH);
        #pragma unroll 2
        for (int k4 = 0; k4 < kH / 4; ++k4) {
            float4 w0 = w04[k4], w1 = w14[k4];
            #pragma unroll
            for (int r = 0; r < 16; ++r) {
                float4 av = *(const float4*)&bufB[rg * 16 + r][k4 * 4];
                a0[r] += w0.x * av.x + w0.y * av.y + w0.z * av.z + w0.w * av.w;
                a1[r] += w1.x * av.x + w1.y * av.y + w1.z * av.z + w1.w * av.w;
            }
        }
        float c0 = fc2b[oc], c1 = fc2b[oc + 128];
        #pragma unroll
        for (int r = 0; r < 16; ++r) {
            bufA[rg * 16 + r][oc] = fmaxf(a0[r] + c0, 0.f);
            bufA[rg * 16 + r][oc + 128] = fmaxf(a1[r] + c1, 0.f);
        }
    }
    __syncthreads();
    {
        const int o3 = tid & 63, kg = tid >> 6;
        float acc[kOR] = {};
        const float4* w4 = (const float4*)(fc3w + o3 * kH + kg * 64);
        #pragma unroll 2
        for (int k4 = 0; k4 < 16; ++k4) {
            float4 wv = w4[k4];
            #pragma unroll
            for (int r = 0; r < kOR; ++r) {
                float4 av = *(const float4*)&bufA[r][kg * 64 + k4 * 4];
                acc[r] += wv.x * av.x + wv.y * av.y + wv.z * av.z + wv.w * av.w;
            }
        }
        float* red = &bufB[0][0];
        #pragma unroll
        for (int r = 0; r < kOR; ++r) red[(kg * kOR + r) * 64 + o3] = acc[r];
        __syncthreads();
        for (int x = tid; x < kOR * 64; x += 256) {
            int r = x >> 6, o = x & 63;
            float s = red[r * 64 + o] + red[(kOR + r) * 64 + o] +
                      red[(2 * kOR + r) * 64 + o] + red[(3 * kOR + r) * 64 + o] +
                      fc3b[o];
            int m = m0 + r;
            int t = m >> 10, bn = m & 1023, b = bn >> 6, n = bn & 63;
            out[((b * kTS + t) * kN + n) * kDout + o] = s;
        }
    }
}

extern "C" void kernel_launch(void* const* d_in, const int* in_sizes, int n_in,
                              void* d_out, int out_size, void* d_ws, size_t ws_size,
                              hipStream_t stream) {
    const float* inputs    = (const float*)d_in[0];
    const float* rel_rec   = (const float*)d_in[1];
    const float* rel_send  = (const float*)d_in[2];
    const float* rel_types = (const float*)d_in[3];
    const float* W1  = (const float*)d_in[4];  const float* b1  = (const float*)d_in[5];
    const float* W2  = (const float*)d_in[6];  const float* b2  = (const float*)d_in[7];
    const float* Wir = (const float*)d_in[8];  const float* bir = (const float*)d_in[9];
    const float* Whr = (const float*)d_in[10]; const float* bhr = (const float*)d_in[11];
    const float* Wii = (const float*)d_in[12]; const float* bii = (const float*)d_in[13];
    const float* Whi = (const float*)d_in[14]; const float* bhi = (const float*)d_in[15];
    const float* Win = (const float*)d_in[16]; const float* bin_ = (const float*)d_in[17];
    const float* Whn = (const float*)d_in[18]; const float* bhn = (const float*)d_in[19];
    const float* fc1w = (const float*)d_in[20]; const float* fc1b = (const float*)d_in[21];
    const float* fc2w = (const float*)d_in[22]; const float* fc2b = (const float*)d_in[23];
    const float* fc3w = (const float*)d_in[24]; const float* fc3b = (const float*)d_in[25];
    float* out = (float*)d_out;

    char* w = (char*)d_ws;
    int* edge_at = (int*)w;            w += ((kN * kN * 4 + 255) / 256) * 256;
    float* ts = (float*)w;             w += ((kB * kE * 4 + 255) / 256) * 256;
    unsigned short* W2h = (unsigned short*)w;  w += kH * kH * 2;
    unsigned short* W2l = (unsigned short*)w;  w += kH * kH * 2;
    float* U = (float*)w;              w += kBN * kH * 4;
    float* V = (float*)w;              w += kBN * kH * 4;
    float* agg = (float*)w;            w += kBN * kH * 4;
    float* hh = (float*)w;             // (kTS+1) * kBN * kH floats (~42 MiB)

    hipMemsetAsync(edge_at, 0xFF, kN * kN * 4, stream);
    setup_kernel<<<kH * kH / 256, 256, 0, stream>>>(rel_rec, rel_send, rel_types,
                                                    W2, edge_at, ts, W2h, W2l);
    hipMemsetAsync(U, 0, kBN * kH * 4, stream);
    hipMemsetAsync(V, 0, kBN * kH * 4, stream);
    hipMemsetAsync(hh, 0, kBN * kH * 4, stream);   // h_0 = 0

    for (int t = 0; t < kTS; ++t) {
        edge_kernel<<<kBN, 256, 0, stream>>>(U, V, W2h, W2l, b1, b2, ts, edge_at, agg);
        gru_uv_kernel<<<kBN / kGR, 256, 0, stream>>>(
            hh + (size_t)t * kBN * kH, agg, inputs, t,
            Wir, bir, Whr, bhr, Wii, bii, Whi, bhi, Win, bin_, Whn, bhn, W1,
            hh + (size_t)(t + 1) * kBN * kH, U, V);
    }
    out_mlp_kernel<<<kTS * kBN / kOR, 256, 0, stream>>>(
        hh + (size_t)kBN * kH, fc1w, fc1b, fc2w, fc2b, fc3w, fc3b, out);
}